// Round 1
// baseline (3812.041 us; speedup 1.0000x reference)
//
#include <hip/hip_runtime.h>

// MassConservingLSTM_MR — persistent 32-block recurrent kernel for MI355X.
//
// T=512 steps, B=512 batch, IN=4, AUX=28, OUT=32, G=64.
// Each block owns 16 batch rows. Cross-block coupling is ONE scalar per step
// (S = sum |c| over all [B,32]); exchanged via per-step slot arrays in d_ws
// with agent-scope atomics (slot value = 1 + partial, 0 = not yet written).
// All gate GEMMs use mfma_f32_16x16x32_bf16 with weight B-fragments resident
// in registers (W_r: 64 VGPR/lane, W_i: 8) or pre-swizzled LDS (small mats).
// The [16,1024] redistribution matrix never leaves registers: relu + row-L1
// (16-lane quad shuffle reduce) + contraction with c happen in C-layout.

#define T_STEPS 512
#define B_DIM 512
#define OUTSZ 8388608ull  // 512*512*32

using bf16v8 = __attribute__((ext_vector_type(8))) short;
using f32v4  = __attribute__((ext_vector_type(4))) float;

__device__ __forceinline__ short f2b(float f) {
  union { float f; unsigned u; } x; x.f = f;
  unsigned r = x.u + 0x7fffu + ((x.u >> 16) & 1u);
  return (short)(r >> 16);
}

__global__ __launch_bounds__(512, 2) void mclstm_persistent(
    const float* __restrict__ g_xm, const float* __restrict__ g_xa,
    const float* __restrict__ g_Wi, const float* __restrict__ g_bi,
    const float* __restrict__ g_Wr, const float* __restrict__ g_br,
    const float* __restrict__ g_Wo, const float* __restrict__ g_bo,
    const float* __restrict__ g_Ws, const float* __restrict__ g_Wrm,
    const float* __restrict__ g_b0, const float* __restrict__ g_lng,
    const float* __restrict__ g_lnb,
    float* __restrict__ out, float* __restrict__ slots) {

  __shared__ __align__(16) float featx[16 * 36];   // [b][k] k<4: xm, else xa
  __shared__ __align__(16) float cstate[16 * 36];  // [b][o]
  __shared__ __align__(16) float gibuf[16 * 132];  // [b][128] raw -> sigmoid
  __shared__ __align__(16) float obuf[16 * 36];    // [b][p] raw -> sigmoid
  __shared__ __align__(16) float ov0buf[16 * 68];  // [b][g]
  __shared__ __align__(16) float ov1buf[16 * 36];  // [b][p]
  __shared__ __align__(16) float mpart[8 * 16 * 36]; // per-wave m_new partials
  __shared__ __align__(16) float s_br[1024];
  __shared__ float s_bi[128], s_bo[32], s_b0[32], s_lng[32], s_lnb[32];
  __shared__ float s_rsi[64], s_wsum[8], s_Sval;
  __shared__ __align__(16) unsigned short tanhb[16 * 72];  // bf16
  __shared__ __align__(16) unsigned short swzWo[4 * 512];  // frag-swizzled
  __shared__ __align__(16) unsigned short swzEx[4 * 512];
  __shared__ __align__(16) unsigned short swzSig[4 * 512];

  const int tid  = threadIdx.x;
  const int blk  = blockIdx.x;
  const int w    = tid >> 6;   // wave 0..7
  const int lane = tid & 63;
  const int q    = lane >> 4;  // quad 0..3
  const int m    = lane & 15;

  // ---------------- startup: weights -> registers / LDS ----------------
  bf16v8 wr[8][2];  // W_r B-frags: wave w owns cols [w*128, w*128+128)
#pragma unroll
  for (int t = 0; t < 8; ++t) {
    const int n = w * 128 + t * 16 + m;
#pragma unroll
    for (int kh = 0; kh < 2; ++kh) {
      const float* gp = g_Wr + n * 64 + kh * 32 + q * 8;
      f32v4 u0 = *(const f32v4*)gp;
      f32v4 u1 = *(const f32v4*)(gp + 4);
      bf16v8 fr;
#pragma unroll
      for (int j = 0; j < 4; ++j) { fr[j] = f2b(u0[j]); fr[4 + j] = f2b(u1[j]); }
      wr[t][kh] = fr;
    }
  }
  bf16v8 wi[2];  // W_i: wave w owns cols [w*16, w*16+16)
  {
    const int n = w * 16 + m;
#pragma unroll
    for (int kh = 0; kh < 2; ++kh) {
      const float* gp = g_Wi + n * 64 + kh * 32 + q * 8;
      f32v4 u0 = *(const f32v4*)gp;
      f32v4 u1 = *(const f32v4*)(gp + 4);
      bf16v8 fr;
#pragma unroll
      for (int j = 0; j < 4; ++j) { fr[j] = f2b(u0[j]); fr[4 + j] = f2b(u1[j]); }
      wi[kh] = fr;
    }
  }
  if (w == 0) {  // W_o frags: B[k][n] = W_o[n][k]
#pragma unroll
    for (int tl = 0; tl < 2; ++tl)
#pragma unroll
      for (int kh = 0; kh < 2; ++kh) {
        bf16v8 fr;
#pragma unroll
        for (int j = 0; j < 8; ++j)
          fr[j] = f2b(g_Wo[(tl * 16 + m) * 64 + kh * 32 + q * 8 + j]);
        *(bf16v8*)&swzWo[(tl * 2 + kh) * 512 + lane * 8] = fr;
      }
  }
  if (w == 1) {  // exp(W_s) frags: B[k=o][n=g] = exp(W_s[o][g]), K=32
#pragma unroll
    for (int tl = 0; tl < 4; ++tl) {
      bf16v8 fr;
#pragma unroll
      for (int j = 0; j < 8; ++j)
        fr[j] = f2b(__expf(g_Ws[(q * 8 + j) * 64 + tl * 16 + m]));
      *(bf16v8*)&swzEx[tl * 512 + lane * 8] = fr;
    }
  }
  if (w == 2) {  // sigmoid(W_rm^T) frags: B[k=g][n=p] = sig(W_rm[p][g])
#pragma unroll
    for (int tl = 0; tl < 2; ++tl)
#pragma unroll
      for (int kh = 0; kh < 2; ++kh) {
        bf16v8 fr;
#pragma unroll
        for (int j = 0; j < 8; ++j) {
          float v = g_Wrm[(tl * 16 + m) * 64 + kh * 32 + q * 8 + j];
          fr[j] = f2b(1.0f / (1.0f + __expf(-v)));
        }
        *(bf16v8*)&swzSig[(tl * 2 + kh) * 512 + lane * 8] = fr;
      }
  }
  for (int i = tid; i < 1024; i += 512) s_br[i] = g_br[i];
  if (tid < 128) s_bi[tid] = g_bi[tid];
  if (tid < 32) {
    s_bo[tid] = g_bo[tid]; s_b0[tid] = g_b0[tid];
    s_lng[tid] = g_lng[tid]; s_lnb[tid] = g_lnb[tid];
  }
  for (int i = tid; i < 16 * 36; i += 512) cstate[i] = 0.0f;
  __syncthreads();

  const f32v4 z4 = {0.f, 0.f, 0.f, 0.f};

  // ---------------- time loop ----------------
  for (int s = 0; s < T_STEPS; ++s) {
    // stage x_t for our 16 rows (independent of the scalar -> before spin)
    {
      const int b = tid >> 5, k = tid & 31;
      const int rg = blk * 16 + b;
      float v = (k < 4) ? g_xm[(size_t)s * 2048 + rg * 4 + k]
                        : g_xa[(size_t)s * 14336 + rg * 28 + (k - 4)];
      featx[b * 36 + k] = v;
    }
    // scalar all-reduce: spin on this step's 32 slots (wave 0 only)
    if (s > 0) {
      if (tid < 64) {
        const float* slot = slots + (size_t)s * 32;
        float v = 1.0f;
        for (int it = 0; it < (1 << 20); ++it) {
          v = (lane < 32)
                  ? __hip_atomic_load(slot + lane, __ATOMIC_RELAXED,
                                      __HIP_MEMORY_SCOPE_AGENT)
                  : 1.0f;
          if (__all(v > 0.5f)) break;
        }
        float sv = (lane < 32) ? (v - 1.0f) : 0.0f;
#pragma unroll
        for (int msk = 1; msk < 64; msk <<= 1) sv += __shfl_xor(sv, msk);
        if (tid == 0) s_Sval = sv;
      }
    } else if (tid == 0) {
      s_Sval = 0.0f;
    }
    __syncthreads();  // sync1: featx, Sval, cstate(prev) visible

    const float inv = 1.0f / (s_Sval + 1e-5f);

    // ---- A fragments: feat = [x | c*inv] ----
    f32v4 x0 = *(const f32v4*)&featx[m * 36 + q * 8];
    f32v4 x1 = *(const f32v4*)&featx[m * 36 + q * 8 + 4];
    f32v4 c0 = *(const f32v4*)&cstate[m * 36 + q * 8];
    f32v4 c1 = *(const f32v4*)&cstate[m * 36 + q * 8 + 4];
    bf16v8 a0, a1;
#pragma unroll
    for (int j = 0; j < 4; ++j) {
      a0[j] = f2b(x0[j]); a0[4 + j] = f2b(x1[j]);
      a1[j] = f2b(c0[j] * inv); a1[4 + j] = f2b(c1[j] * inv);
    }

    // ---- GEMM1: W_r, W_i, W_o, exp_Ws ----
    f32v4 racc[8];
#pragma unroll
    for (int t = 0; t < 8; ++t) {
      racc[t] = __builtin_amdgcn_mfma_f32_16x16x32_bf16(a0, wr[t][0], z4, 0, 0, 0);
      racc[t] = __builtin_amdgcn_mfma_f32_16x16x32_bf16(a1, wr[t][1], racc[t], 0, 0, 0);
    }
    f32v4 gacc = __builtin_amdgcn_mfma_f32_16x16x32_bf16(a0, wi[0], z4, 0, 0, 0);
    gacc = __builtin_amdgcn_mfma_f32_16x16x32_bf16(a1, wi[1], gacc, 0, 0, 0);
    if (w < 2) {
      bf16v8 bo0 = *(const bf16v8*)&swzWo[(w * 2 + 0) * 512 + lane * 8];
      bf16v8 bo1 = *(const bf16v8*)&swzWo[(w * 2 + 1) * 512 + lane * 8];
      f32v4 oacc = __builtin_amdgcn_mfma_f32_16x16x32_bf16(a0, bo0, z4, 0, 0, 0);
      oacc = __builtin_amdgcn_mfma_f32_16x16x32_bf16(a1, bo1, oacc, 0, 0, 0);
#pragma unroll
      for (int r = 0; r < 4; ++r) obuf[(q * 4 + r) * 36 + w * 16 + m] = oacc[r];
    }
    if (w >= 4) {  // ov0 = (c*inv - b0) @ exp_Ws, K=32
      bf16v8 a2;
#pragma unroll
      for (int j = 0; j < 4; ++j) {
        a2[j]     = f2b(c0[j] * inv - s_b0[q * 8 + j]);
        a2[4 + j] = f2b(c1[j] * inv - s_b0[q * 8 + 4 + j]);
      }
      bf16v8 be = *(const bf16v8*)&swzEx[(w - 4) * 512 + lane * 8];
      f32v4 eacc = __builtin_amdgcn_mfma_f32_16x16x32_bf16(a2, be, z4, 0, 0, 0);
#pragma unroll
      for (int r = 0; r < 4; ++r) ov0buf[(q * 4 + r) * 68 + (w - 4) * 16 + m] = eacc[r];
    }
#pragma unroll
    for (int r = 0; r < 4; ++r) gibuf[(q * 4 + r) * 132 + w * 16 + m] = gacc[r];

    // ---- in-register r epilogue: relu+bias, row-L1 sums, c-contraction ----
#pragma unroll
    for (int t = 0; t < 8; ++t) {
      float brt = s_br[w * 128 + t * 16 + m];
#pragma unroll
      for (int r = 0; r < 4; ++r) racc[t][r] = fmaxf(racc[t][r] + brt, 0.0f);
    }
    float part[4][2] = {{0.f, 0.f}, {0.f, 0.f}, {0.f, 0.f}, {0.f, 0.f}};
#pragma unroll
    for (int ol = 0; ol < 4; ++ol) {  // o = w*4 + ol
      float sr0 = racc[2 * ol][0] + racc[2 * ol + 1][0];
      float sr1 = racc[2 * ol][1] + racc[2 * ol + 1][1];
      float sr2 = racc[2 * ol][2] + racc[2 * ol + 1][2];
      float sr3 = racc[2 * ol][3] + racc[2 * ol + 1][3];
#pragma unroll
      for (int msk = 1; msk < 16; msk <<= 1) {  // 16-lane quad-group reduce
        sr0 += __shfl_xor(sr0, msk); sr1 += __shfl_xor(sr1, msk);
        sr2 += __shfl_xor(sr2, msk); sr3 += __shfl_xor(sr3, msk);
      }
      float cr0 = cstate[(q * 4 + 0) * 36 + w * 4 + ol] / fmaxf(sr0, 1e-12f);
      float cr1 = cstate[(q * 4 + 1) * 36 + w * 4 + ol] / fmaxf(sr1, 1e-12f);
      float cr2 = cstate[(q * 4 + 2) * 36 + w * 4 + ol] / fmaxf(sr2, 1e-12f);
      float cr3 = cstate[(q * 4 + 3) * 36 + w * 4 + ol] / fmaxf(sr3, 1e-12f);
#pragma unroll
      for (int ph = 0; ph < 2; ++ph) {
        const int t = 2 * ol + ph;
        part[0][ph] += racc[t][0] * cr0;
        part[1][ph] += racc[t][1] * cr1;
        part[2][ph] += racc[t][2] * cr2;
        part[3][ph] += racc[t][3] * cr3;
      }
    }
#pragma unroll
    for (int r = 0; r < 4; ++r)
#pragma unroll
      for (int ph = 0; ph < 2; ++ph)
        mpart[w * 576 + (q * 4 + r) * 36 + ph * 16 + m] = part[r][ph];
    __syncthreads();  // sync2

    // ---- E1a: pointwise sigmoids / tanh ----
#pragma unroll
    for (int it = 0; it < 4; ++it) {
      const int idx = tid + it * 512;
      const int bb = idx >> 7, nn = idx & 127;
      float v = gibuf[bb * 132 + nn] + s_bi[nn];
      gibuf[bb * 132 + nn] = 1.0f / (1.0f + __expf(-v));
    }
    {
      const int bb = tid >> 5, pp = tid & 31;
      float v = obuf[bb * 36 + pp] + s_bo[pp];
      obuf[bb * 36 + pp] = 1.0f / (1.0f + __expf(-v));
    }
#pragma unroll
    for (int it = 0; it < 2; ++it) {
      const int idx = tid + it * 512;
      const int bb = idx >> 6, gg = idx & 63;
      float xx = ov0buf[bb * 68 + gg];
      float e = __expf(2.0f * xx);
      tanhb[bb * 72 + gg] = (unsigned short)f2b(1.0f - 2.0f / (e + 1.0f));
    }
    __syncthreads();  // sync2b

    // ---- GEMM2: ov1 = tanh(ov0) @ sig_Wr (waves 0-1) ; rs_i (wave 7) ----
    if (w < 2) {
      bf16v8 a30 = *(const bf16v8*)&tanhb[m * 72 + q * 8];
      bf16v8 a31 = *(const bf16v8*)&tanhb[m * 72 + 32 + q * 8];
      bf16v8 bs0 = *(const bf16v8*)&swzSig[(w * 2 + 0) * 512 + lane * 8];
      bf16v8 bs1 = *(const bf16v8*)&swzSig[(w * 2 + 1) * 512 + lane * 8];
      f32v4 v1 = __builtin_amdgcn_mfma_f32_16x16x32_bf16(a30, bs0, z4, 0, 0, 0);
      v1 = __builtin_amdgcn_mfma_f32_16x16x32_bf16(a31, bs1, v1, 0, 0, 0);
#pragma unroll
      for (int r = 0; r < 4; ++r) ov1buf[(q * 4 + r) * 36 + w * 16 + m] = v1[r];
    }
    if (w == 7) {
      const int bb = lane >> 2, ii = lane & 3;
      float ssum = 0.0f;
      for (int p2 = 0; p2 < 32; ++p2) ssum += gibuf[bb * 132 + ii * 32 + p2];
      s_rsi[bb * 4 + ii] = 1.0f / fmaxf(ssum, 1e-12f);
    }
    __syncthreads();  // sync4

    // ---- E2: layernorm, MR, m_new, outputs, new state ----
    {
      const int b = tid >> 5, p = tid & 31;
      float x = ov1buf[b * 36 + p];
      float s1 = x, s2 = x * x;
#pragma unroll
      for (int msk = 1; msk < 32; msk <<= 1) {
        s1 += __shfl_xor(s1, msk); s2 += __shfl_xor(s2, msk);
      }
      float mu = s1 * 0.03125f;
      float var = s2 * 0.03125f - mu * mu;
      float ln = (x - mu) * rsqrtf(fmaxf(var, 0.0f) + 1e-5f) * s_lng[p] + s_lnb[p];
      float o = obuf[b * 36 + p];
      float f = 1.0f - o;
      float MR = fmaxf(fminf(ln, f), f - 1.0f);
      float mn = 0.0f;
#pragma unroll
      for (int w2 = 0; w2 < 8; ++w2) mn += mpart[w2 * 576 + b * 36 + p];
#pragma unroll
      for (int ii = 0; ii < 4; ++ii)
        mn += featx[b * 36 + ii] * gibuf[b * 132 + ii * 32 + p] * s_rsi[b * 4 + ii];
      float op = o + MR;
      float h = o * mn;
      float cn = (1.0f - op) * mn;
      float mrf = MR * mn;
      const size_t base = (size_t)s * 16384 + (size_t)(blk * 16 + b) * 32 + p;
      out[base] = h;
      out[OUTSZ + base] = cn;
      out[2 * OUTSZ + base] = o;
      out[3 * OUTSZ + base] = MR;
      out[4 * OUTSZ + base] = op;
      out[5 * OUTSZ + base] = mrf;
      out[6 * OUTSZ + base] = h;
      cstate[b * 36 + p] = cn;
      float aw = fabsf(cn);
#pragma unroll
      for (int msk = 1; msk < 64; msk <<= 1) aw += __shfl_xor(aw, msk);
      if ((tid & 63) == 0) s_wsum[tid >> 6] = aw;
    }
    __syncthreads();  // sync5

    if (tid == 0 && s + 1 < T_STEPS) {
      float P = 0.0f;
#pragma unroll
      for (int i = 0; i < 8; ++i) P += s_wsum[i];
      __hip_atomic_store(slots + (size_t)(s + 1) * 32 + blk, 1.0f + P,
                         __ATOMIC_RELEASE, __HIP_MEMORY_SCOPE_AGENT);
    }
  }
}

extern "C" void kernel_launch(void* const* d_in, const int* in_sizes, int n_in,
                              void* d_out, int out_size, void* d_ws, size_t ws_size,
                              hipStream_t stream) {
  (void)in_sizes; (void)n_in; (void)out_size; (void)ws_size;
  const float* xm  = (const float*)d_in[0];
  const float* xa  = (const float*)d_in[1];
  const float* Wi  = (const float*)d_in[2];
  const float* bi  = (const float*)d_in[3];
  const float* Wr  = (const float*)d_in[4];
  const float* br  = (const float*)d_in[5];
  const float* Wo  = (const float*)d_in[6];
  const float* bo  = (const float*)d_in[7];
  const float* Ws  = (const float*)d_in[8];
  const float* Wrm = (const float*)d_in[9];
  const float* b0  = (const float*)d_in[10];
  const float* lng = (const float*)d_in[11];
  const float* lnb = (const float*)d_in[12];
  float* slots = (float*)d_ws;

  // zero the per-step all-reduce slots (d_ws is poisoned 0xAA before each run)
  hipMemsetAsync(d_ws, 0, (size_t)T_STEPS * 32 * sizeof(float), stream);
  mclstm_persistent<<<dim3(32), dim3(512), 0, stream>>>(
      xm, xa, Wi, bi, Wr, br, Wo, bo, Ws, Wrm, b0, lng, lnb,
      (float*)d_out, slots);
}

// Round 2
// 2814.454 us; speedup vs baseline: 1.3545x; 1.3545x over previous
//
#include <hip/hip_runtime.h>

// MassConservingLSTM_MR — persistent 32-block recurrent kernel, round 2.
// Key restructure vs R1: feat@W is split across MFMA K-halves so ALL matrix
// work (x-part and raw-c-part) runs BEFORE the cross-block scalar arrives;
// post-spin work is one FMA/element + shuffle reductions. Publishes are
// RELAXED per-wave atomics into a sign-tagged 2-phase slot buffer (no vmcnt
// drain on the critical path). 3 barriers/step, out-stores deferred a step.

#define T_STEPS 512
#define OUTSZ 8388608ull  // 512*512*32

using bf16v8 = __attribute__((ext_vector_type(8))) short;
using f32v4  = __attribute__((ext_vector_type(4))) float;

__device__ __forceinline__ short f2b(float f) {
  union { float f; unsigned u; } x; x.f = f;
  unsigned r = x.u + 0x7fffu + ((x.u >> 16) & 1u);
  return (short)(r >> 16);
}
__device__ __forceinline__ float rcpf(float x) { return __builtin_amdgcn_rcpf(x); }

__global__ __launch_bounds__(512, 2) void mclstm_persistent(
    const float* __restrict__ g_xm, const float* __restrict__ g_xa,
    const float* __restrict__ g_Wi, const float* __restrict__ g_bi,
    const float* __restrict__ g_Wr, const float* __restrict__ g_br,
    const float* __restrict__ g_Wo, const float* __restrict__ g_bo,
    const float* __restrict__ g_Ws, const float* __restrict__ g_Wrm,
    const float* __restrict__ g_b0, const float* __restrict__ g_lng,
    const float* __restrict__ g_lnb,
    float* __restrict__ out, float* __restrict__ slots) {

  __shared__ __align__(16) float featx[2][16 * 36];  // double-buffered x
  __shared__ __align__(16) float cstate[16 * 36];
  __shared__ __align__(16) float gibuf[16 * 132];    // sigmoid(i) values
  __shared__ __align__(16) float obuf[16 * 36];
  __shared__ __align__(16) float ov1buf[16 * 36];
  __shared__ __align__(16) float mpart[8][16 * 36];  // per-wave m_new r-partials
  __shared__ __align__(16) float isump[128];         // [wave][b] i-gate p-sums
  __shared__ __align__(16) unsigned short tanhb[16 * 72];
  __shared__ __align__(16) unsigned short swzSig[4 * 512];  // GEMM2 B-frags
  __shared__ float s_bvec[64], s_lng[32], s_lnb[32];

  const int tid  = threadIdx.x;
  const int blk  = blockIdx.x;
  const int w    = tid >> 6;
  const int lane = tid & 63;
  const int q    = lane >> 4;
  const int m    = lane & 15;
  const f32v4 z4 = {0.f, 0.f, 0.f, 0.f};

  // ---------------- startup ----------------
  bf16v8 wr0[8], wr1[8];
  float brv[8];
#pragma unroll
  for (int t = 0; t < 8; ++t) {
    const int n = w * 128 + t * 16 + m;
    brv[t] = g_br[n];
#pragma unroll
    for (int kh = 0; kh < 2; ++kh) {
      const float* gp = g_Wr + n * 64 + kh * 32 + q * 8;
      f32v4 u0 = *(const f32v4*)gp;
      f32v4 u1 = *(const f32v4*)(gp + 4);
      bf16v8 fr;
#pragma unroll
      for (int j = 0; j < 4; ++j) { fr[j] = f2b(u0[j]); fr[4 + j] = f2b(u1[j]); }
      if (kh == 0) wr0[t] = fr; else wr1[t] = fr;
    }
  }
  bf16v8 wi0, wi1;
  const float gb = g_bi[w * 16 + m];
  {
    const int n = w * 16 + m;
#pragma unroll
    for (int kh = 0; kh < 2; ++kh) {
      const float* gp = g_Wi + n * 64 + kh * 32 + q * 8;
      f32v4 u0 = *(const f32v4*)gp;
      f32v4 u1 = *(const f32v4*)(gp + 4);
      bf16v8 fr;
#pragma unroll
      for (int j = 0; j < 4; ++j) { fr[j] = f2b(u0[j]); fr[4 + j] = f2b(u1[j]); }
      if (kh == 0) wi0 = fr; else wi1 = fr;
    }
  }
  bf16v8 bo0 = {0,0,0,0,0,0,0,0}, bo1 = bo0, be = bo0;
  float bov = 0.f;
  if (w < 2) {  // W_o B-frags + sigmoid(W_rm^T) frags -> LDS
    const int n = w * 16 + m;
    bov = g_bo[n];
#pragma unroll
    for (int kh = 0; kh < 2; ++kh) {
      bf16v8 fr, fs;
#pragma unroll
      for (int j = 0; j < 8; ++j) {
        fr[j] = f2b(g_Wo[n * 64 + kh * 32 + q * 8 + j]);
        float v = g_Wrm[n * 64 + kh * 32 + q * 8 + j];
        fs[j] = f2b(rcpf(1.0f + __expf(-v)));
      }
      if (kh == 0) bo0 = fr; else bo1 = fr;
      *(bf16v8*)&swzSig[(w * 2 + kh) * 512 + lane * 8] = fs;
    }
  }
  if (w >= 4) {  // exp(W_s) B-frags, K=32 (k = o)
    const int n = (w - 4) * 16 + m;
    bf16v8 fr;
#pragma unroll
    for (int j = 0; j < 8; ++j) fr[j] = f2b(__expf(g_Ws[(q * 8 + j) * 64 + n]));
    be = fr;
  }
  if (tid < 64) {  // bvec[g] = b0 @ exp_Ws  (constant across steps)
    float a = 0.f;
    for (int o = 0; o < 32; ++o) a += g_b0[o] * __expf(g_Ws[o * 64 + tid]);
    s_bvec[tid] = a;
  }
  if (tid < 32) { s_lng[tid] = g_lng[tid]; s_lnb[tid] = g_lnb[tid]; }
  for (int i = tid; i < 16 * 36; i += 512) cstate[i] = 0.0f;
  {  // stage x_0
    const int b2 = tid >> 5, k2 = tid & 31, rg = blk * 16 + b2;
    featx[0][b2 * 36 + k2] =
        (k2 < 4) ? g_xm[rg * 4 + k2] : g_xa[rg * 28 + k2 - 4];
  }
  __syncthreads();
  float bvl = (w >= 4) ? s_bvec[(w - 4) * 16 + m] : 0.f;

  float ph_h = 0, ph_cn = 0, ph_o = 0, ph_MR = 0, ph_op = 0, ph_mrf = 0;
  size_t ph_base = 0;

  // ---------------- time loop ----------------
  for (int s = 0; s < T_STEPS; ++s) {
    // deferred out-stores for step s-1 (drain during the spin slack)
    if (s > 0) {
      out[ph_base] = ph_h;
      out[OUTSZ + ph_base] = ph_cn;
      out[2 * OUTSZ + ph_base] = ph_o;
      out[3 * OUTSZ + ph_base] = ph_MR;
      out[4 * OUTSZ + ph_base] = ph_op;
      out[5 * OUTSZ + ph_base] = ph_mrf;
      out[6 * OUTSZ + ph_base] = ph_h;
    }
    // prefetch x_{s+1}
    const int b2 = tid >> 5, k2 = tid & 31;
    const int sp = (s + 1 < T_STEPS) ? s + 1 : T_STEPS - 1;
    const float xv = (k2 < 4)
        ? g_xm[(size_t)sp * 2048 + (blk * 16 + b2) * 4 + k2]
        : g_xa[(size_t)sp * 14336 + (blk * 16 + b2) * 28 + k2 - 4];

    // ---- A-frags (x-half, raw-c-half) ----
    const float* fx = featx[s & 1];
    f32v4 x0 = *(const f32v4*)&fx[m * 36 + q * 8];
    f32v4 x1 = *(const f32v4*)&fx[m * 36 + q * 8 + 4];
    f32v4 c0 = *(const f32v4*)&cstate[m * 36 + q * 8];
    f32v4 c1 = *(const f32v4*)&cstate[m * 36 + q * 8 + 4];
    bf16v8 a0, a1;
#pragma unroll
    for (int j = 0; j < 4; ++j) {
      a0[j] = f2b(x0[j]); a0[4 + j] = f2b(x1[j]);
      a1[j] = f2b(c0[j]); a1[4 + j] = f2b(c1[j]);
    }

    // ---- GEMM1 (all inv-independent; bias seeded via C-operand) ----
    f32v4 rx[8], rc[8];
#pragma unroll
    for (int t = 0; t < 8; ++t) {
      f32v4 cb = {brv[t], brv[t], brv[t], brv[t]};
      rx[t] = __builtin_amdgcn_mfma_f32_16x16x32_bf16(a0, wr0[t], cb, 0, 0, 0);
      rc[t] = __builtin_amdgcn_mfma_f32_16x16x32_bf16(a1, wr1[t], z4, 0, 0, 0);
    }
    f32v4 gxb = {gb, gb, gb, gb};
    f32v4 gxv = __builtin_amdgcn_mfma_f32_16x16x32_bf16(a0, wi0, gxb, 0, 0, 0);
    f32v4 gcv = __builtin_amdgcn_mfma_f32_16x16x32_bf16(a1, wi1, z4, 0, 0, 0);
    f32v4 oxv = z4, ocv = z4, ev = z4;
    if (w < 2) {
      f32v4 ob = {bov, bov, bov, bov};
      oxv = __builtin_amdgcn_mfma_f32_16x16x32_bf16(a0, bo0, ob, 0, 0, 0);
      ocv = __builtin_amdgcn_mfma_f32_16x16x32_bf16(a1, bo1, z4, 0, 0, 0);
    }
    if (w >= 4) {
      ev = __builtin_amdgcn_mfma_f32_16x16x32_bf16(a1, be, z4, 0, 0, 0);
    }
    // c values for the r-contraction (cstate stable until E2)
    f32v4 c4[4];
#pragma unroll
    for (int r = 0; r < 4; ++r)
      c4[r] = *(const f32v4*)&cstate[(q * 4 + r) * 36 + w * 4];
    // stage x_{s+1} (waitcnt absorbed by spin slack)
    featx[(s + 1) & 1][b2 * 36 + k2] = xv;

    // ---- spin: all waves poll 256 per-wave partials (4/lane) ----
    float inv_;
    if (s > 0) {
      const float e = ((s >> 1) & 1) ? -1.0f : 1.0f;
      float* sl = slots + (s & 1) * 256 + lane * 4;
      float v0 = 0, v1 = 0, v2 = 0, v3 = 0;
      for (int it = 0; it < (1 << 18); ++it) {
        v0 = __hip_atomic_load(sl + 0, __ATOMIC_RELAXED, __HIP_MEMORY_SCOPE_AGENT);
        v1 = __hip_atomic_load(sl + 1, __ATOMIC_RELAXED, __HIP_MEMORY_SCOPE_AGENT);
        v2 = __hip_atomic_load(sl + 2, __ATOMIC_RELAXED, __HIP_MEMORY_SCOPE_AGENT);
        v3 = __hip_atomic_load(sl + 3, __ATOMIC_RELAXED, __HIP_MEMORY_SCOPE_AGENT);
        if (__all((v0 * e > 0.5f) && (v1 * e > 0.5f) &&
                  (v2 * e > 0.5f) && (v3 * e > 0.5f))) break;
        __builtin_amdgcn_s_sleep(1);
      }
      float sv = (v0 + v1 + v2 + v3) * e - 4.0f;
#pragma unroll
      for (int msk = 1; msk < 64; msk <<= 1) sv += __shfl_xor(sv, msk);
      inv_ = rcpf(sv + 1e-5f);
    } else {
      inv_ = rcpf(1e-5f);
    }

    // ---- post-spin epilogues (short critical path) ----
    if (w >= 4) {  // MR path: tanh(ev*inv - bvec) -> bf16 -> tanhb
#pragma unroll
      for (int r = 0; r < 4; ++r) {
        float t0 = ev[r] * inv_ - bvl;
        float ex = __expf(2.0f * t0);
        float th = 1.0f - 2.0f * rcpf(ex + 1.0f);
        tanhb[(q * 4 + r) * 72 + (w - 4) * 16 + m] = (unsigned short)f2b(th);
      }
    }
    if (w < 2) {  // o-gate
#pragma unroll
      for (int r = 0; r < 4; ++r) {
        float t0 = oxv[r] + ocv[r] * inv_;
        obuf[(q * 4 + r) * 36 + w * 16 + m] = rcpf(1.0f + __expf(-t0));
      }
    }
    {  // i-gate: sigmoid + in-register p-sums
      float sg0, sg1, sg2, sg3;
      {
        float t0 = gxv[0] + gcv[0] * inv_; sg0 = rcpf(1.0f + __expf(-t0));
        t0 = gxv[1] + gcv[1] * inv_; sg1 = rcpf(1.0f + __expf(-t0));
        t0 = gxv[2] + gcv[2] * inv_; sg2 = rcpf(1.0f + __expf(-t0));
        t0 = gxv[3] + gcv[3] * inv_; sg3 = rcpf(1.0f + __expf(-t0));
      }
      gibuf[(q * 4 + 0) * 132 + w * 16 + m] = sg0;
      gibuf[(q * 4 + 1) * 132 + w * 16 + m] = sg1;
      gibuf[(q * 4 + 2) * 132 + w * 16 + m] = sg2;
      gibuf[(q * 4 + 3) * 132 + w * 16 + m] = sg3;
#pragma unroll
      for (int msk = 1; msk < 16; msk <<= 1) {
        sg0 += __shfl_xor(sg0, msk); sg1 += __shfl_xor(sg1, msk);
        sg2 += __shfl_xor(sg2, msk); sg3 += __shfl_xor(sg3, msk);
      }
      if (m == 0) {
        f32v4 sv4 = {sg0, sg1, sg2, sg3};
        *(f32v4*)&isump[w * 16 + q * 4] = sv4;
      }
    }
    {  // r epilogue: combine+relu, row-L1, contract with c
      f32v4 rr[8];
#pragma unroll
      for (int t = 0; t < 8; ++t)
#pragma unroll
        for (int r = 0; r < 4; ++r)
          rr[t][r] = fmaxf(fmaf(rc[t][r], inv_, rx[t][r]), 0.0f);
      float p0[4] = {0, 0, 0, 0}, p1[4] = {0, 0, 0, 0};
#pragma unroll
      for (int ol = 0; ol < 4; ++ol) {
        float s0 = rr[2 * ol][0] + rr[2 * ol + 1][0];
        float s1 = rr[2 * ol][1] + rr[2 * ol + 1][1];
        float s2 = rr[2 * ol][2] + rr[2 * ol + 1][2];
        float s3 = rr[2 * ol][3] + rr[2 * ol + 1][3];
#pragma unroll
        for (int msk = 1; msk < 16; msk <<= 1) {
          s0 += __shfl_xor(s0, msk); s1 += __shfl_xor(s1, msk);
          s2 += __shfl_xor(s2, msk); s3 += __shfl_xor(s3, msk);
        }
        float cr0 = c4[0][ol] * rcpf(fmaxf(s0, 1e-12f));
        float cr1 = c4[1][ol] * rcpf(fmaxf(s1, 1e-12f));
        float cr2 = c4[2][ol] * rcpf(fmaxf(s2, 1e-12f));
        float cr3 = c4[3][ol] * rcpf(fmaxf(s3, 1e-12f));
        p0[0] += rr[2 * ol][0] * cr0; p1[0] += rr[2 * ol + 1][0] * cr0;
        p0[1] += rr[2 * ol][1] * cr1; p1[1] += rr[2 * ol + 1][1] * cr1;
        p0[2] += rr[2 * ol][2] * cr2; p1[2] += rr[2 * ol + 1][2] * cr2;
        p0[3] += rr[2 * ol][3] * cr3; p1[3] += rr[2 * ol + 1][3] * cr3;
      }
#pragma unroll
      for (int r = 0; r < 4; ++r) {
        mpart[w][(q * 4 + r) * 36 + m] = p0[r];
        mpart[w][(q * 4 + r) * 36 + 16 + m] = p1[r];
      }
    }
    __syncthreads();  // B1: tanhb/mpart/gibuf/isump/obuf visible

    if (w < 2) {  // GEMM2: ov1 = tanh(ov0) @ sig_Wr
      bf16v8 a30 = *(const bf16v8*)&tanhb[m * 72 + q * 8];
      bf16v8 a31 = *(const bf16v8*)&tanhb[m * 72 + 32 + q * 8];
      bf16v8 bs0 = *(const bf16v8*)&swzSig[(w * 2 + 0) * 512 + lane * 8];
      bf16v8 bs1 = *(const bf16v8*)&swzSig[(w * 2 + 1) * 512 + lane * 8];
      f32v4 v1v = __builtin_amdgcn_mfma_f32_16x16x32_bf16(a30, bs0, z4, 0, 0, 0);
      v1v = __builtin_amdgcn_mfma_f32_16x16x32_bf16(a31, bs1, v1v, 0, 0, 0);
#pragma unroll
      for (int r = 0; r < 4; ++r)
        ov1buf[(q * 4 + r) * 36 + w * 16 + m] = v1v[r];
    }
    __syncthreads();  // B2

    {  // ---- E2: LN, MR, m_new, state update, publish ----
      const int b = tid >> 5, p = tid & 31;
      float x = ov1buf[b * 36 + p];
      float s1 = x, s2 = x * x;
#pragma unroll
      for (int msk = 1; msk < 32; msk <<= 1) {
        s1 += __shfl_xor(s1, msk); s2 += __shfl_xor(s2, msk);
      }
      float mu = s1 * 0.03125f;
      float var = s2 * 0.03125f - mu * mu;
      float ln = (x - mu) * __builtin_amdgcn_rsqf(fmaxf(var, 0.0f) + 1e-5f) *
                     s_lng[p] + s_lnb[p];
      float o = obuf[b * 36 + p];
      float f = 1.0f - o;
      float MR = fmaxf(fminf(ln, f), f - 1.0f);
      float mn = 0.0f;
#pragma unroll
      for (int w2 = 0; w2 < 8; ++w2) mn += mpart[w2][b * 36 + p];
#pragma unroll
      for (int ii = 0; ii < 4; ++ii) {
        float rsi = rcpf(fmaxf(isump[(2 * ii) * 16 + b] +
                               isump[(2 * ii + 1) * 16 + b], 1e-12f));
        mn += fx[b * 36 + ii] * gibuf[b * 132 + ii * 32 + p] * rsi;
      }
      float op = o + MR;
      ph_h = o * mn;
      ph_cn = (1.0f - op) * mn;
      ph_o = o; ph_MR = MR; ph_op = op;
      ph_mrf = MR * mn;
      ph_base = (size_t)s * 16384 + (size_t)(blk * 16 + b) * 32 + p;
      cstate[b * 36 + p] = ph_cn;
      float aw = fabsf(ph_cn);
#pragma unroll
      for (int msk = 1; msk < 64; msk <<= 1) aw += __shfl_xor(aw, msk);
      if (lane == 0 && s + 1 < T_STEPS) {
        const float tag = (((s + 1) >> 1) & 1) ? -1.0f : 1.0f;
        __hip_atomic_store(slots + ((s + 1) & 1) * 256 + blk * 8 + w,
                           tag * (1.0f + aw), __ATOMIC_RELAXED,
                           __HIP_MEMORY_SCOPE_AGENT);
      }
    }
    __syncthreads();  // B3: cstate for next iteration
  }
  // final stores for s = T_STEPS-1
  out[ph_base] = ph_h;
  out[OUTSZ + ph_base] = ph_cn;
  out[2 * OUTSZ + ph_base] = ph_o;
  out[3 * OUTSZ + ph_base] = ph_MR;
  out[4 * OUTSZ + ph_base] = ph_op;
  out[5 * OUTSZ + ph_base] = ph_mrf;
  out[6 * OUTSZ + ph_base] = ph_h;
}

extern "C" void kernel_launch(void* const* d_in, const int* in_sizes, int n_in,
                              void* d_out, int out_size, void* d_ws, size_t ws_size,
                              hipStream_t stream) {
  (void)in_sizes; (void)n_in; (void)out_size; (void)ws_size;
  const float* xm  = (const float*)d_in[0];
  const float* xa  = (const float*)d_in[1];
  const float* Wi  = (const float*)d_in[2];
  const float* bi  = (const float*)d_in[3];
  const float* Wr  = (const float*)d_in[4];
  const float* br  = (const float*)d_in[5];
  const float* Wo  = (const float*)d_in[6];
  const float* bo  = (const float*)d_in[7];
  const float* Ws  = (const float*)d_in[8];
  const float* Wrm = (const float*)d_in[9];
  const float* b0  = (const float*)d_in[10];
  const float* lng = (const float*)d_in[11];
  const float* lnb = (const float*)d_in[12];
  float* slots = (float*)d_ws;

  // 2-phase slot buffer: 2*256 floats; 0 = not-ready under either sign tag
  hipMemsetAsync(d_ws, 0, 2 * 256 * sizeof(float), stream);
  mclstm_persistent<<<dim3(32), dim3(512), 0, stream>>>(
      xm, xa, Wi, bi, Wr, br, Wo, bo, Ws, Wrm, b0, lng, lnb,
      (float*)d_out, slots);
}